// Round 5
// baseline (693.015 us; speedup 1.0000x reference)
//
#include <hip/hip_runtime.h>
#include <math.h>

// TAGConv 2-layer GNN on MI355X.
// R5 hybrid: layer 1 = chain props (x,Ax,A2x,A3x) + ONE fused K=512 matmul
// (h-tile-only LDS staging, 42KB -> 3 blocks/CU, W from L2) writing hid once.
// Layer 2 = Horner on 64-wide arrays (mm_y<64> + 3 fused props).

#define N_NODES 50000
#define N_EDGES 800000
#define NB_SCAN 196          // ceil(50000/256)

// ---------------- graph preprocessing ----------------

__global__ void count_deg_kernel(const int* __restrict__ col, int* __restrict__ deg, int e) {
    int i = blockIdx.x * 256 + threadIdx.x;
    if (i < e) atomicAdd(&deg[col[i]], 1);
}

__global__ void scan1_kernel(const int* __restrict__ deg, int* __restrict__ bsum,
                             float* __restrict__ dinv) {
    __shared__ int sd[256];
    int tid = threadIdx.x;
    int i = blockIdx.x * 256 + tid;
    int v = (i < N_NODES) ? deg[i] : 0;
    if (i < N_NODES) dinv[i] = (v > 0) ? (1.0f / sqrtf((float)v)) : 0.f;
    sd[tid] = v;
    __syncthreads();
    for (int o = 128; o > 0; o >>= 1) {
        if (tid < o) sd[tid] += sd[tid + o];
        __syncthreads();
    }
    if (tid == 0) bsum[blockIdx.x] = sd[0];
}

__global__ void scan2_kernel(int* __restrict__ bsum) {
    __shared__ int sd[256];
    int tid = threadIdx.x;
    int v = (tid < NB_SCAN) ? bsum[tid] : 0;
    sd[tid] = v;
    __syncthreads();
    for (int o = 1; o < 256; o <<= 1) {
        int t = (tid >= o) ? sd[tid - o] : 0;
        __syncthreads();
        sd[tid] += t;
        __syncthreads();
    }
    if (tid < NB_SCAN) bsum[tid] = sd[tid] - v;   // exclusive
}

__global__ void scan3_kernel(const int* __restrict__ deg, const int* __restrict__ bsum,
                             int* __restrict__ off, int* __restrict__ cursor) {
    __shared__ int sd[256];
    int tid = threadIdx.x;
    int i = blockIdx.x * 256 + tid;
    int v = (i < N_NODES) ? deg[i] : 0;
    sd[tid] = v;
    __syncthreads();
    for (int o = 1; o < 256; o <<= 1) {
        int t = (tid >= o) ? sd[tid - o] : 0;
        __syncthreads();
        sd[tid] += t;
        __syncthreads();
    }
    if (i < N_NODES) {
        int val = bsum[blockIdx.x] + sd[tid] - v;
        off[i] = val;
        cursor[i] = val;
    }
    if (i == N_NODES - 1) off[N_NODES] = N_EDGES;
}

__global__ void scatter_csr_kernel(const int* __restrict__ row, const int* __restrict__ col,
                                   const float* __restrict__ dinv, int* __restrict__ cursor,
                                   int2* __restrict__ meta, int e) {
    int i = blockIdx.x * 256 + threadIdx.x;
    if (i < e) {
        int r = row[i], c = col[i];
        int p = atomicAdd(&cursor[c], 1);
        float w = dinv[r] * dinv[c];
        meta[p] = make_int2(r, __float_as_int(w));
    }
}

// ------------- mm_fused4: out = relu(sum_hop h_hop(80x128) @ W[hop] + bias) -------------
// Full 128-col span per block; only the h tile is staged (42KB LDS -> 3 blocks/CU);
// W read from global (L2-resident). 256 threads = 16 tx (col quads) x 16 ty (5-row grp).
__global__ __launch_bounds__(256) void mm_fused4(const float* __restrict__ h0,
                                                 const float* __restrict__ h1,
                                                 const float* __restrict__ h2,
                                                 const float* __restrict__ h3,
                                                 const float* __restrict__ W,   // [4][128][128]
                                                 const float* __restrict__ bias,
                                                 float* __restrict__ outp) {
    constexpr int WOUT = 128, NQ = 2;
    __shared__ float hs[80 * 132];
    const int tid = threadIdx.x;
    const int tx = tid & 15;
    const int ty = tid >> 4;
    const int row0 = blockIdx.x * 80;
    const int rbase = ty * 5;

    float4 acc[5][NQ];
#pragma unroll
    for (int r = 0; r < 5; ++r)
#pragma unroll
        for (int q = 0; q < NQ; ++q) acc[r][q] = make_float4(0.f, 0.f, 0.f, 0.f);

#pragma unroll
    for (int hop = 0; hop < 4; ++hop) {
        const float* hp = (hop == 0) ? h0 : (hop == 1) ? h1 : (hop == 2) ? h2 : h3;
        if (hop) __syncthreads();   // protect LDS before restage
        const float4* srcv = (const float4*)(hp + (size_t)row0 * 128);
        for (int i = tid; i < 2560; i += 256) {
            int r = i >> 5, c = i & 31;
            *(float4*)&hs[r * 132 + c * 4] = srcv[i];
        }
        __syncthreads();

        const float4* Wv = (const float4*)(W + (size_t)hop * 128 * WOUT);
#pragma unroll 2
        for (int k4 = 0; k4 < 32; ++k4) {
            float4 wv[4][NQ];
#pragma unroll
            for (int kk = 0; kk < 4; ++kk)
#pragma unroll
                for (int q = 0; q < NQ; ++q)
                    wv[kk][q] = Wv[(size_t)(k4 * 4 + kk) * (WOUT / 4) + q * 16 + tx];
#pragma unroll
            for (int r = 0; r < 5; ++r) {
                float4 hv = *(const float4*)&hs[(rbase + r) * 132 + k4 * 4];
#pragma unroll
                for (int q = 0; q < NQ; ++q) {
                    acc[r][q].x += hv.x * wv[0][q].x + hv.y * wv[1][q].x + hv.z * wv[2][q].x + hv.w * wv[3][q].x;
                    acc[r][q].y += hv.x * wv[0][q].y + hv.y * wv[1][q].y + hv.z * wv[2][q].y + hv.w * wv[3][q].y;
                    acc[r][q].z += hv.x * wv[0][q].z + hv.y * wv[1][q].z + hv.z * wv[2][q].z + hv.w * wv[3][q].z;
                    acc[r][q].w += hv.x * wv[0][q].w + hv.y * wv[1][q].w + hv.z * wv[2][q].w + hv.w * wv[3][q].w;
                }
            }
        }
    }

    float4 bv[NQ];
#pragma unroll
    for (int q = 0; q < NQ; ++q) bv[q] = *(const float4*)&bias[q * 64 + tx * 4];

#pragma unroll
    for (int r = 0; r < 5; ++r) {
        float* op = outp + (size_t)(row0 + rbase + r) * WOUT;
#pragma unroll
        for (int q = 0; q < NQ; ++q) {
            float4 v = acc[r][q];
            v.x = fmaxf(v.x + bv[q].x, 0.f);
            v.y = fmaxf(v.y + bv[q].y, 0.f);
            v.z = fmaxf(v.z + bv[q].z, 0.f);
            v.w = fmaxf(v.w + bv[q].w, 0.f);
            *(float4*)&op[q * 64 + tx * 4] = v;
        }
    }
}

// ---------------- mm_y: y[hop] = h @ W[hop], hop = blockIdx&3 (64-wide out) ----------------
__global__ __launch_bounds__(256) void mm_y64(const float* __restrict__ h,
                                              const float* __restrict__ W,   // [4][128][64]
                                              float* __restrict__ y) {       // [4][N][64]
    constexpr int WOUT = 64;
    __shared__ float hs[80 * 132];
    const int tid = threadIdx.x;
    const int tx = tid & 15;
    const int ty = tid >> 4;
    const int tile = blockIdx.x >> 2;
    const int hop = blockIdx.x & 3;
    const int row0 = tile * 80;

    const float4* srcv = (const float4*)(h + (size_t)row0 * 128);
    for (int i = tid; i < 2560; i += 256) {
        int r = i >> 5, c = i & 31;
        *(float4*)&hs[r * 132 + c * 4] = srcv[i];
    }
    __syncthreads();

    const float4* Wv = (const float4*)(W + (size_t)hop * 128 * WOUT);

    float4 acc[5];
#pragma unroll
    for (int r = 0; r < 5; ++r) acc[r] = make_float4(0.f, 0.f, 0.f, 0.f);

    const int rbase = ty * 5;
#pragma unroll 2
    for (int k4 = 0; k4 < 32; ++k4) {
        float4 wv[4];
#pragma unroll
        for (int kk = 0; kk < 4; ++kk)
            wv[kk] = Wv[(size_t)(k4 * 4 + kk) * (WOUT / 4) + tx];
#pragma unroll
        for (int r = 0; r < 5; ++r) {
            float4 hv = *(const float4*)&hs[(rbase + r) * 132 + k4 * 4];
            acc[r].x += hv.x * wv[0].x + hv.y * wv[1].x + hv.z * wv[2].x + hv.w * wv[3].x;
            acc[r].y += hv.x * wv[0].y + hv.y * wv[1].y + hv.z * wv[2].y + hv.w * wv[3].y;
            acc[r].z += hv.x * wv[0].z + hv.y * wv[1].z + hv.z * wv[2].z + hv.w * wv[3].z;
            acc[r].w += hv.x * wv[0].w + hv.y * wv[1].w + hv.z * wv[2].w + hv.w * wv[3].w;
        }
    }

    float* yp = y + (size_t)hop * N_NODES * WOUT;
#pragma unroll
    for (int r = 0; r < 5; ++r)
        *(float4*)&yp[(size_t)(row0 + rbase + r) * WOUT + tx * 4] = acc[r];
}

// -------- prop128: out = A*h (+ yadd) (+bias,relu). 1 node / 64-lane wave (float2/lane).
template <int EPI, bool HASY>   // EPI: 0 = none, 1 = +bias, relu
__global__ void prop128(const float* __restrict__ h, const int* __restrict__ off,
                        const int2* __restrict__ meta, const float* __restrict__ yadd,
                        const float* __restrict__ bias, float* __restrict__ out) {
    int node = blockIdx.x * 4 + (threadIdx.x >> 6);
    int lane = threadIdx.x & 63;
    int s = off[node], e = off[node + 1];
    const float2* h2 = (const float2*)h;
    float2 a0 = make_float2(0.f, 0.f), a1 = make_float2(0.f, 0.f);
    int j = s;
    for (; j + 3 < e; j += 4) {
        int2 m0 = meta[j], m1 = meta[j + 1], m2 = meta[j + 2], m3 = meta[j + 3];
        float2 v0 = h2[m0.x * 64 + lane];
        float2 v1 = h2[m1.x * 64 + lane];
        float2 v2 = h2[m2.x * 64 + lane];
        float2 v3 = h2[m3.x * 64 + lane];
        float w0 = __int_as_float(m0.y), w1 = __int_as_float(m1.y);
        float w2 = __int_as_float(m2.y), w3 = __int_as_float(m3.y);
        a0.x += w0 * v0.x + w1 * v1.x;
        a0.y += w0 * v0.y + w1 * v1.y;
        a1.x += w2 * v2.x + w3 * v3.x;
        a1.y += w2 * v2.y + w3 * v3.y;
    }
    for (; j < e; ++j) {
        int2 m0 = meta[j];
        float2 v0 = h2[m0.x * 64 + lane];
        float w0 = __int_as_float(m0.y);
        a0.x += w0 * v0.x;
        a0.y += w0 * v0.y;
    }
    float2 r = make_float2(a0.x + a1.x, a0.y + a1.y);
    if (HASY) {
        float2 yv = ((const float2*)yadd)[node * 64 + lane];
        r.x += yv.x;
        r.y += yv.y;
    }
    if (EPI == 1) {
        float2 bv = ((const float2*)bias)[lane];
        r.x = fmaxf(r.x + bv.x, 0.f);
        r.y = fmaxf(r.y + bv.y, 0.f);
    }
    ((float2*)out)[node * 64 + lane] = r;
}

// -------- prop64: 64-wide arrays, 2 nodes / wave (32 lanes x float2 each).
template <int EPI>   // 0 = plain accumulate, 2 = +bias, log_softmax
__global__ void prop64(const float* __restrict__ h, const int* __restrict__ off,
                       const int2* __restrict__ meta, const float* __restrict__ yadd,
                       const float* __restrict__ bias, float* __restrict__ out) {
    int tid = threadIdx.x;
    int node = blockIdx.x * 8 + (tid >> 5);
    int l32 = tid & 31;
    int s = off[node], e = off[node + 1];
    const float2* h2 = (const float2*)h;   // 32 float2 per 64-wide row
    float2 a0 = make_float2(0.f, 0.f), a1 = make_float2(0.f, 0.f);
    int j = s;
    for (; j + 3 < e; j += 4) {
        int2 m0 = meta[j], m1 = meta[j + 1], m2 = meta[j + 2], m3 = meta[j + 3];
        float2 v0 = h2[m0.x * 32 + l32];
        float2 v1 = h2[m1.x * 32 + l32];
        float2 v2 = h2[m2.x * 32 + l32];
        float2 v3 = h2[m3.x * 32 + l32];
        float w0 = __int_as_float(m0.y), w1 = __int_as_float(m1.y);
        float w2 = __int_as_float(m2.y), w3 = __int_as_float(m3.y);
        a0.x += w0 * v0.x + w1 * v1.x;
        a0.y += w0 * v0.y + w1 * v1.y;
        a1.x += w2 * v2.x + w3 * v3.x;
        a1.y += w2 * v2.y + w3 * v3.y;
    }
    for (; j < e; ++j) {
        int2 m0 = meta[j];
        float2 v0 = h2[m0.x * 32 + l32];
        float w0 = __int_as_float(m0.y);
        a0.x += w0 * v0.x;
        a0.y += w0 * v0.y;
    }
    float2 yv = ((const float2*)yadd)[node * 32 + l32];
    float2 v = make_float2(a0.x + a1.x + yv.x, a0.y + a1.y + yv.y);
    if (EPI == 2) {
        float2 bv = ((const float2*)bias)[l32];
        v.x += bv.x; v.y += bv.y;
        float m = fmaxf(v.x, v.y);
        for (int d = 1; d < 32; d <<= 1) m = fmaxf(m, __shfl_xor(m, d));
        float su = expf(v.x - m) + expf(v.y - m);
        for (int d = 1; d < 32; d <<= 1) su += __shfl_xor(su, d);
        float l = m + logf(su);
        v.x -= l; v.y -= l;
    }
    ((float2*)out)[node * 32 + l32] = v;
}

// ---------------- launch ----------------

extern "C" void kernel_launch(void* const* d_in, const int* in_sizes, int n_in,
                              void* d_out, int out_size, void* d_ws, size_t ws_size,
                              hipStream_t stream) {
    const float* x  = (const float*)d_in[0];
    const int*   ei = (const int*)d_in[1];
    const float* W1 = (const float*)d_in[2];
    const float* b1 = (const float*)d_in[3];
    const float* W2 = (const float*)d_in[4];
    const float* b2 = (const float*)d_in[5];
    float* out = (float*)d_out;

    const int* row = ei;             // edge_index[0]
    const int* col = ei + N_EDGES;   // edge_index[1]

    char* ws_base = (char*)d_ws;
    size_t o = 0;
    auto carve = [&](size_t bytes) {
        void* p = ws_base + o;
        o = (o + bytes + 511) & ~(size_t)511;
        return p;
    };
    int*   deg    = (int*)carve(N_NODES * 4);
    float* dinv   = (float*)carve(N_NODES * 4);
    int*   off    = (int*)carve((N_NODES + 1) * 4);
    int*   cursor = (int*)carve(N_NODES * 4);
    int*   bsum   = (int*)carve(NB_SCAN * 4);
    int2*  meta   = (int2*)carve((size_t)N_EDGES * 8);
    float* A      = (float*)carve((size_t)N_NODES * 128 * 4);
    float* B      = (float*)carve((size_t)N_NODES * 128 * 4);
    float* C      = (float*)carve((size_t)N_NODES * 128 * 4);
    float* hid    = (float*)carve((size_t)N_NODES * 128 * 4);
    float* y2     = (float*)carve((size_t)4 * N_NODES * 64 * 4);   // [4][N][64]
    float* T2     = (float*)carve((size_t)N_NODES * 64 * 4);

    float* y2_0 = y2;
    float* y2_1 = y2 + (size_t)1 * N_NODES * 64;
    float* y2_2 = y2 + (size_t)2 * N_NODES * 64;
    float* y2_3 = y2 + (size_t)3 * N_NODES * 64;
    float* S2   = y2_3;   // reuse once y2_3 is consumed

    const int nb_e = (N_EDGES + 255) / 256;   // 3125

    // graph preprocessing
    hipMemsetAsync(deg, 0, N_NODES * 4, stream);
    count_deg_kernel<<<nb_e, 256, 0, stream>>>(col, deg, N_EDGES);
    scan1_kernel<<<NB_SCAN, 256, 0, stream>>>(deg, bsum, dinv);
    scan2_kernel<<<1, 256, 0, stream>>>(bsum);
    scan3_kernel<<<NB_SCAN, 256, 0, stream>>>(deg, bsum, off, cursor);
    scatter_csr_kernel<<<nb_e, 256, 0, stream>>>(row, col, dinv, cursor, meta, N_EDGES);

    // ----- layer 1: chain props, then one fused K=512 matmul -> hid
    prop128<0, false><<<12500, 256, 0, stream>>>(x, off, meta, nullptr, nullptr, A);
    prop128<0, false><<<12500, 256, 0, stream>>>(A, off, meta, nullptr, nullptr, B);
    prop128<0, false><<<12500, 256, 0, stream>>>(B, off, meta, nullptr, nullptr, C);
    mm_fused4<<<625, 256, 0, stream>>>(x, A, B, C, W1, b1, hid);

    // ----- layer 2 (Horner): out = log_softmax(z0 + A(z1 + A(z2 + A z3)) + b2)
    mm_y64<<<2500, 256, 0, stream>>>(hid, W2, y2);
    prop64<0><<<6250, 256, 0, stream>>>(y2_3, off, meta, y2_2, nullptr, T2);
    prop64<0><<<6250, 256, 0, stream>>>(T2,   off, meta, y2_1, nullptr, S2);
    prop64<2><<<6250, 256, 0, stream>>>(S2,   off, meta, y2_0, b2,      out);
}

// Round 6
// 582.875 us; speedup vs baseline: 1.1890x; 1.1890x over previous
//
#include <hip/hip_runtime.h>
#include <math.h>

// TAGConv 2-layer GNN on MI355X.
// R6: layer 1 = chain props + column-split fused K=512 mm (grid 1250, h-only
// LDS 42KB -> 3 blocks/CU, W from L2) -- fixes R5's 625-block grid starvation.
// Props: unroll 8 (8 gathers in flight), scalarized meta loads via
// readfirstlane, hoisted y-add, prop64 = 1 node/wave (no degree divergence).
// Layer 2 stays Horner on 64-wide arrays.

#define N_NODES 50000
#define N_EDGES 800000
#define NB_SCAN 196          // ceil(50000/256)

// ---------------- graph preprocessing ----------------

__global__ void count_deg_kernel(const int* __restrict__ col, int* __restrict__ deg, int e) {
    int i = blockIdx.x * 256 + threadIdx.x;
    if (i < e) atomicAdd(&deg[col[i]], 1);
}

__global__ void scan1_kernel(const int* __restrict__ deg, int* __restrict__ bsum,
                             float* __restrict__ dinv) {
    __shared__ int sd[256];
    int tid = threadIdx.x;
    int i = blockIdx.x * 256 + tid;
    int v = (i < N_NODES) ? deg[i] : 0;
    if (i < N_NODES) dinv[i] = (v > 0) ? (1.0f / sqrtf((float)v)) : 0.f;
    sd[tid] = v;
    __syncthreads();
    for (int o = 128; o > 0; o >>= 1) {
        if (tid < o) sd[tid] += sd[tid + o];
        __syncthreads();
    }
    if (tid == 0) bsum[blockIdx.x] = sd[0];
}

__global__ void scan2_kernel(int* __restrict__ bsum) {
    __shared__ int sd[256];
    int tid = threadIdx.x;
    int v = (tid < NB_SCAN) ? bsum[tid] : 0;
    sd[tid] = v;
    __syncthreads();
    for (int o = 1; o < 256; o <<= 1) {
        int t = (tid >= o) ? sd[tid - o] : 0;
        __syncthreads();
        sd[tid] += t;
        __syncthreads();
    }
    if (tid < NB_SCAN) bsum[tid] = sd[tid] - v;   // exclusive
}

__global__ void scan3_kernel(const int* __restrict__ deg, const int* __restrict__ bsum,
                             int* __restrict__ off, int* __restrict__ cursor) {
    __shared__ int sd[256];
    int tid = threadIdx.x;
    int i = blockIdx.x * 256 + tid;
    int v = (i < N_NODES) ? deg[i] : 0;
    sd[tid] = v;
    __syncthreads();
    for (int o = 1; o < 256; o <<= 1) {
        int t = (tid >= o) ? sd[tid - o] : 0;
        __syncthreads();
        sd[tid] += t;
        __syncthreads();
    }
    if (i < N_NODES) {
        int val = bsum[blockIdx.x] + sd[tid] - v;
        off[i] = val;
        cursor[i] = val;
    }
    if (i == N_NODES - 1) off[N_NODES] = N_EDGES;
}

__global__ void scatter_csr_kernel(const int* __restrict__ row, const int* __restrict__ col,
                                   const float* __restrict__ dinv, int* __restrict__ cursor,
                                   int2* __restrict__ meta, int e) {
    int i = blockIdx.x * 256 + threadIdx.x;
    if (i < e) {
        int r = row[i], c = col[i];
        int p = atomicAdd(&cursor[c], 1);
        float w = dinv[r] * dinv[c];
        meta[p] = make_int2(r, __float_as_int(w));
    }
}

// ------- mm_chain4: out = relu(sum_hop h_hop(80x128) @ W[hop][:, c0:c0+64] + bias) -------
// grid (625, 2): blockIdx.y picks the 64-col panel. Only the h tile is staged
// (42KB LDS -> 3 blocks/CU); W read from global (L2-resident, L1-broadcast over ty).
__global__ __launch_bounds__(256) void mm_chain4(const float* __restrict__ h0,
                                                 const float* __restrict__ h1,
                                                 const float* __restrict__ h2,
                                                 const float* __restrict__ h3,
                                                 const float* __restrict__ W,   // [4][128][128]
                                                 const float* __restrict__ bias,
                                                 float* __restrict__ outp) {
    __shared__ float hs[80 * 132];
    const int tid = threadIdx.x;
    const int tx = tid & 15;
    const int ty = tid >> 4;
    const int row0 = blockIdx.x * 80;
    const int c0 = blockIdx.y * 64;
    const int rbase = ty * 5;

    float4 acc[5];
#pragma unroll
    for (int r = 0; r < 5; ++r) acc[r] = make_float4(0.f, 0.f, 0.f, 0.f);

#pragma unroll
    for (int hop = 0; hop < 4; ++hop) {
        const float* hp = (hop == 0) ? h0 : (hop == 1) ? h1 : (hop == 2) ? h2 : h3;
        if (hop) __syncthreads();   // protect LDS before restage
        const float4* srcv = (const float4*)(hp + (size_t)row0 * 128);
        for (int i = tid; i < 2560; i += 256) {
            int r = i >> 5, c = i & 31;
            *(float4*)&hs[r * 132 + c * 4] = srcv[i];
        }
        __syncthreads();

        const float* wp = W + (size_t)hop * 128 * 128 + c0;
#pragma unroll 2
        for (int k4 = 0; k4 < 32; ++k4) {
            float4 wv[4];
#pragma unroll
            for (int kk = 0; kk < 4; ++kk)
                wv[kk] = *(const float4*)&wp[(size_t)(k4 * 4 + kk) * 128 + tx * 4];
#pragma unroll
            for (int r = 0; r < 5; ++r) {
                float4 hv = *(const float4*)&hs[(rbase + r) * 132 + k4 * 4];
                acc[r].x += hv.x * wv[0].x + hv.y * wv[1].x + hv.z * wv[2].x + hv.w * wv[3].x;
                acc[r].y += hv.x * wv[0].y + hv.y * wv[1].y + hv.z * wv[2].y + hv.w * wv[3].y;
                acc[r].z += hv.x * wv[0].z + hv.y * wv[1].z + hv.z * wv[2].z + hv.w * wv[3].z;
                acc[r].w += hv.x * wv[0].w + hv.y * wv[1].w + hv.z * wv[2].w + hv.w * wv[3].w;
            }
        }
    }

    float4 bv = *(const float4*)&bias[c0 + tx * 4];
#pragma unroll
    for (int r = 0; r < 5; ++r) {
        float4 v = acc[r];
        v.x = fmaxf(v.x + bv.x, 0.f);
        v.y = fmaxf(v.y + bv.y, 0.f);
        v.z = fmaxf(v.z + bv.z, 0.f);
        v.w = fmaxf(v.w + bv.w, 0.f);
        *(float4*)&outp[(size_t)(row0 + rbase + r) * 128 + c0 + tx * 4] = v;
    }
}

// ---------------- mm_y64: y[hop] = h @ W[hop], hop = blockIdx&3 (64-wide out) -----------
__global__ __launch_bounds__(256) void mm_y64(const float* __restrict__ h,
                                              const float* __restrict__ W,   // [4][128][64]
                                              float* __restrict__ y) {       // [4][N][64]
    constexpr int WOUT = 64;
    __shared__ float hs[80 * 132];
    const int tid = threadIdx.x;
    const int tx = tid & 15;
    const int ty = tid >> 4;
    const int tile = blockIdx.x >> 2;
    const int hop = blockIdx.x & 3;
    const int row0 = tile * 80;

    const float4* srcv = (const float4*)(h + (size_t)row0 * 128);
    for (int i = tid; i < 2560; i += 256) {
        int r = i >> 5, c = i & 31;
        *(float4*)&hs[r * 132 + c * 4] = srcv[i];
    }
    __syncthreads();

    const float4* Wv = (const float4*)(W + (size_t)hop * 128 * WOUT);

    float4 acc[5];
#pragma unroll
    for (int r = 0; r < 5; ++r) acc[r] = make_float4(0.f, 0.f, 0.f, 0.f);

    const int rbase = ty * 5;
#pragma unroll 2
    for (int k4 = 0; k4 < 32; ++k4) {
        float4 wv[4];
#pragma unroll
        for (int kk = 0; kk < 4; ++kk)
            wv[kk] = Wv[(size_t)(k4 * 4 + kk) * (WOUT / 4) + tx];
#pragma unroll
        for (int r = 0; r < 5; ++r) {
            float4 hv = *(const float4*)&hs[(rbase + r) * 132 + k4 * 4];
            acc[r].x += hv.x * wv[0].x + hv.y * wv[1].x + hv.z * wv[2].x + hv.w * wv[3].x;
            acc[r].y += hv.x * wv[0].y + hv.y * wv[1].y + hv.z * wv[2].y + hv.w * wv[3].y;
            acc[r].z += hv.x * wv[0].z + hv.y * wv[1].z + hv.z * wv[2].z + hv.w * wv[3].z;
            acc[r].w += hv.x * wv[0].w + hv.y * wv[1].w + hv.z * wv[2].w + hv.w * wv[3].w;
        }
    }

    float* yp = y + (size_t)hop * N_NODES * WOUT;
#pragma unroll
    for (int r = 0; r < 5; ++r)
        *(float4*)&yp[(size_t)(row0 + rbase + r) * WOUT + tx * 4] = acc[r];
}

// -------- prop128: out = A*h (+ yadd) (+bias,relu). 1 node / 64-lane wave, float2/lane.
// 8 gathers in flight; CSR range scalarized so meta loads go s_load.
template <int EPI, bool HASY>   // EPI: 0 = none, 1 = +bias, relu
__global__ void prop128(const float* __restrict__ h, const int* __restrict__ off,
                        const int2* __restrict__ meta, const float* __restrict__ yadd,
                        const float* __restrict__ bias, float* __restrict__ out) {
    int node = blockIdx.x * 4 + (threadIdx.x >> 6);
    int lane = threadIdx.x & 63;
    int s = __builtin_amdgcn_readfirstlane(off[node]);
    int e = __builtin_amdgcn_readfirstlane(off[node + 1]);
    const float2* h2 = (const float2*)h;

    float2 yv = make_float2(0.f, 0.f);
    if (HASY) yv = ((const float2*)yadd)[node * 64 + lane];

    float2 a0 = make_float2(0.f, 0.f), a1 = make_float2(0.f, 0.f);
    float2 a2 = make_float2(0.f, 0.f), a3 = make_float2(0.f, 0.f);
    int j = s;
    for (; j + 7 < e; j += 8) {
        int2 m0 = meta[j],     m1 = meta[j + 1], m2 = meta[j + 2], m3 = meta[j + 3];
        int2 m4 = meta[j + 4], m5 = meta[j + 5], m6 = meta[j + 6], m7 = meta[j + 7];
        float2 v0 = h2[m0.x * 64 + lane];
        float2 v1 = h2[m1.x * 64 + lane];
        float2 v2 = h2[m2.x * 64 + lane];
        float2 v3 = h2[m3.x * 64 + lane];
        float2 v4 = h2[m4.x * 64 + lane];
        float2 v5 = h2[m5.x * 64 + lane];
        float2 v6 = h2[m6.x * 64 + lane];
        float2 v7 = h2[m7.x * 64 + lane];
        a0.x += __int_as_float(m0.y) * v0.x + __int_as_float(m1.y) * v1.x;
        a0.y += __int_as_float(m0.y) * v0.y + __int_as_float(m1.y) * v1.y;
        a1.x += __int_as_float(m2.y) * v2.x + __int_as_float(m3.y) * v3.x;
        a1.y += __int_as_float(m2.y) * v2.y + __int_as_float(m3.y) * v3.y;
        a2.x += __int_as_float(m4.y) * v4.x + __int_as_float(m5.y) * v5.x;
        a2.y += __int_as_float(m4.y) * v4.y + __int_as_float(m5.y) * v5.y;
        a3.x += __int_as_float(m6.y) * v6.x + __int_as_float(m7.y) * v7.x;
        a3.y += __int_as_float(m6.y) * v6.y + __int_as_float(m7.y) * v7.y;
    }
    for (; j + 1 < e; j += 2) {
        int2 m0 = meta[j], m1 = meta[j + 1];
        float2 v0 = h2[m0.x * 64 + lane];
        float2 v1 = h2[m1.x * 64 + lane];
        a0.x += __int_as_float(m0.y) * v0.x + __int_as_float(m1.y) * v1.x;
        a0.y += __int_as_float(m0.y) * v0.y + __int_as_float(m1.y) * v1.y;
    }
    if (j < e) {
        int2 m0 = meta[j];
        float2 v0 = h2[m0.x * 64 + lane];
        a1.x += __int_as_float(m0.y) * v0.x;
        a1.y += __int_as_float(m0.y) * v0.y;
    }
    float2 r = make_float2((a0.x + a1.x) + (a2.x + a3.x) + yv.x,
                           (a0.y + a1.y) + (a2.y + a3.y) + yv.y);
    if (EPI == 1) {
        float2 bv = ((const float2*)bias)[lane];
        r.x = fmaxf(r.x + bv.x, 0.f);
        r.y = fmaxf(r.y + bv.y, 0.f);
    }
    ((float2*)out)[node * 64 + lane] = r;
}

// -------- prop64: 64-wide arrays. 1 node / 64-lane wave, float/lane (no divergence).
template <int EPI>   // 0 = plain accumulate, 2 = +bias, log_softmax
__global__ void prop64(const float* __restrict__ h, const int* __restrict__ off,
                       const int2* __restrict__ meta, const float* __restrict__ yadd,
                       const float* __restrict__ bias, float* __restrict__ out) {
    int node = blockIdx.x * 4 + (threadIdx.x >> 6);
    int lane = threadIdx.x & 63;
    int s = __builtin_amdgcn_readfirstlane(off[node]);
    int e = __builtin_amdgcn_readfirstlane(off[node + 1]);

    float yv = yadd[node * 64 + lane];   // hoisted

    float a0 = 0.f, a1 = 0.f, a2 = 0.f, a3 = 0.f;
    int j = s;
    for (; j + 7 < e; j += 8) {
        int2 m0 = meta[j],     m1 = meta[j + 1], m2 = meta[j + 2], m3 = meta[j + 3];
        int2 m4 = meta[j + 4], m5 = meta[j + 5], m6 = meta[j + 6], m7 = meta[j + 7];
        float v0 = h[m0.x * 64 + lane];
        float v1 = h[m1.x * 64 + lane];
        float v2 = h[m2.x * 64 + lane];
        float v3 = h[m3.x * 64 + lane];
        float v4 = h[m4.x * 64 + lane];
        float v5 = h[m5.x * 64 + lane];
        float v6 = h[m6.x * 64 + lane];
        float v7 = h[m7.x * 64 + lane];
        a0 += __int_as_float(m0.y) * v0 + __int_as_float(m1.y) * v1;
        a1 += __int_as_float(m2.y) * v2 + __int_as_float(m3.y) * v3;
        a2 += __int_as_float(m4.y) * v4 + __int_as_float(m5.y) * v5;
        a3 += __int_as_float(m6.y) * v6 + __int_as_float(m7.y) * v7;
    }
    for (; j + 1 < e; j += 2) {
        int2 m0 = meta[j], m1 = meta[j + 1];
        float v0 = h[m0.x * 64 + lane];
        float v1 = h[m1.x * 64 + lane];
        a0 += __int_as_float(m0.y) * v0 + __int_as_float(m1.y) * v1;
    }
    if (j < e) {
        int2 m0 = meta[j];
        a1 += __int_as_float(m0.y) * h[m0.x * 64 + lane];
    }
    float v = (a0 + a1) + (a2 + a3) + yv;
    if (EPI == 2) {
        v += bias[lane];
        float m = v;
        for (int d = 32; d > 0; d >>= 1) m = fmaxf(m, __shfl_xor(m, d));
        float su = expf(v - m);
        for (int d = 32; d > 0; d >>= 1) su += __shfl_xor(su, d);
        v = (v - m) - logf(su);
    }
    out[node * 64 + lane] = v;
}

// ---------------- launch ----------------

extern "C" void kernel_launch(void* const* d_in, const int* in_sizes, int n_in,
                              void* d_out, int out_size, void* d_ws, size_t ws_size,
                              hipStream_t stream) {
    const float* x  = (const float*)d_in[0];
    const int*   ei = (const int*)d_in[1];
    const float* W1 = (const float*)d_in[2];
    const float* b1 = (const float*)d_in[3];
    const float* W2 = (const float*)d_in[4];
    const float* b2 = (const float*)d_in[5];
    float* out = (float*)d_out;

    const int* row = ei;             // edge_index[0]
    const int* col = ei + N_EDGES;   // edge_index[1]

    char* ws_base = (char*)d_ws;
    size_t o = 0;
    auto carve = [&](size_t bytes) {
        void* p = ws_base + o;
        o = (o + bytes + 511) & ~(size_t)511;
        return p;
    };
    int*   deg    = (int*)carve(N_NODES * 4);
    float* dinv   = (float*)carve(N_NODES * 4);
    int*   off    = (int*)carve((N_NODES + 1) * 4);
    int*   cursor = (int*)carve(N_NODES * 4);
    int*   bsum   = (int*)carve(NB_SCAN * 4);
    int2*  meta   = (int2*)carve((size_t)N_EDGES * 8);
    float* A      = (float*)carve((size_t)N_NODES * 128 * 4);
    float* B      = (float*)carve((size_t)N_NODES * 128 * 4);
    float* C      = (float*)carve((size_t)N_NODES * 128 * 4);
    float* hid    = (float*)carve((size_t)N_NODES * 128 * 4);
    float* y2     = (float*)carve((size_t)4 * N_NODES * 64 * 4);   // [4][N][64]
    float* T2     = (float*)carve((size_t)N_NODES * 64 * 4);

    float* y2_0 = y2;
    float* y2_1 = y2 + (size_t)1 * N_NODES * 64;
    float* y2_2 = y2 + (size_t)2 * N_NODES * 64;
    float* y2_3 = y2 + (size_t)3 * N_NODES * 64;
    float* S2   = y2_3;   // reuse once y2_3 is consumed

    const int nb_e = (N_EDGES + 255) / 256;   // 3125

    // graph preprocessing
    hipMemsetAsync(deg, 0, N_NODES * 4, stream);
    count_deg_kernel<<<nb_e, 256, 0, stream>>>(col, deg, N_EDGES);
    scan1_kernel<<<NB_SCAN, 256, 0, stream>>>(deg, bsum, dinv);
    scan2_kernel<<<1, 256, 0, stream>>>(bsum);
    scan3_kernel<<<NB_SCAN, 256, 0, stream>>>(deg, bsum, off, cursor);
    scatter_csr_kernel<<<nb_e, 256, 0, stream>>>(row, col, dinv, cursor, meta, N_EDGES);

    // ----- layer 1: chain props, then one fused K=512 matmul -> hid
    prop128<0, false><<<12500, 256, 0, stream>>>(x, off, meta, nullptr, nullptr, A);
    prop128<0, false><<<12500, 256, 0, stream>>>(A, off, meta, nullptr, nullptr, B);
    prop128<0, false><<<12500, 256, 0, stream>>>(B, off, meta, nullptr, nullptr, C);
    mm_chain4<<<dim3(625, 2), 256, 0, stream>>>(x, A, B, C, W1, b1, hid);

    // ----- layer 2 (Horner): out = log_softmax(z0 + A(z1 + A(z2 + A z3)) + b2)
    mm_y64<<<2500, 256, 0, stream>>>(hid, W2, y2);
    prop64<0><<<12500, 256, 0, stream>>>(y2_3, off, meta, y2_2, nullptr, T2);
    prop64<0><<<12500, 256, 0, stream>>>(T2,   off, meta, y2_1, nullptr, S2);
    prop64<2><<<12500, 256, 0, stream>>>(S2,   off, meta, y2_0, b2,      out);
}